// Round 1
// 630.243 us; speedup vs baseline: 1.2373x; 1.2373x over previous
//
#include <hip/hip_runtime.h>

// PairWiseWeightSmoothLoss — B=64, T=512, V=512, BETA=0.1, PAD=0, normalize by
// count of (target==PAD) positions.
//
// Per position n: contrib_n = s*(dot(M,x) - lse*rowsum) + (src - s*M[t])*(x[t]-lse)
//   with M = matric[forth[n], tgt[n], :], s = 1 - 0.9^(1/L[b]), src = 1 - s*rowsum.
// loss = sum over non-PAD of (-contrib) / count(PAD).
//
// Structure (v2): atomic-free. 2048 blocks x 4 waves; each wave owns 4 positions
// (n = wgid + p*stride). Wave writes its (sum, count) partial to a unique ws slot
// -> no memset, no atomics, no __syncthreads in the main kernel. A single
// 256-thread block reduces the 2*8192 partials and writes the loss.

#define T_DIM 512
#define V_DIM 512
#define LN_0_9 (-0.1053605157f) // ln(0.9)

__device__ __forceinline__ float pick4(float4 v, int k) {
    // v[k] with wave-uniform k, no dynamic register indexing (2 cndmask)
    const float lo = (k & 1) ? v.y : v.x;
    const float hi = (k & 1) ? v.w : v.z;
    return (k & 2) ? hi : lo;
}

__global__ __launch_bounds__(256) void pwl_main_kernel(
    const float* __restrict__ input,   // [N, V]
    const int*   __restrict__ target,  // [N]
    const float* __restrict__ length,  // [B]
    const float* __restrict__ matric,  // [V, V, V]
    float*       __restrict__ ws,      // [2*nwaves]: ws[w]=sum(contrib), ws[nwaves+w]=count
    int N, int nwaves)
{
    const int lane = threadIdx.x & 63;
    const int wave = threadIdx.x >> 6;
    const int wgid = blockIdx.x * 4 + wave;

    // ---- preload targets for all 4 positions (wave-uniform scalar loads) ----
    int ts[4], fs[4];
    #pragma unroll
    for (int p = 0; p < 4; ++p) {
        const int n = wgid + p * nwaves;
        if (n < N) {
            ts[p] = target[n];
            const int tp = n & (T_DIM - 1);
            fs[p] = (tp == 0) ? 0 : target[n - 1];
        } else {
            ts[p] = -1;   // sentinel: skip entirely (not PAD)
            fs[p] = 0;
        }
    }

    float acc_sum = 0.0f;   // identical across lanes (butterfly reduces)
    int   acc_cnt = 0;

    #pragma unroll
    for (int p = 0; p < 4; ++p) {
        const int n = wgid + p * nwaves;
        const int t = ts[p];
        if (t < 0) continue;          // n >= N
        if (t == 0) { acc_cnt++; continue; }   // PAD position

        const int b = n / T_DIM;
        const int f = fs[p];

        // ---- load x row: lane covers v in [4*lane,4*lane+4) and [256+4*lane,...) ----
        const float4* xrow = (const float4*)(input + (size_t)n * V_DIM);
        const float4 x0 = xrow[lane];
        const float4 x1 = xrow[lane + 64];

        // ---- gathered confusion row (independent of softmax; issues early) ----
        const float4* mrow = (const float4*)(matric + ((size_t)f * V_DIM + t) * V_DIM);
        const float4 m0 = mrow[lane];
        const float4 m1 = mrow[lane + 64];

        // ---- wave max ----
        float mx = fmaxf(fmaxf(fmaxf(x0.x, x0.y), fmaxf(x0.z, x0.w)),
                         fmaxf(fmaxf(x1.x, x1.y), fmaxf(x1.z, x1.w)));
        #pragma unroll
        for (int off = 32; off > 0; off >>= 1)
            mx = fmaxf(mx, __shfl_xor(mx, off, 64));

        // ---- wave sum exp(x - mx) ----
        float se = expf(x0.x - mx) + expf(x0.y - mx) + expf(x0.z - mx) + expf(x0.w - mx)
                 + expf(x1.x - mx) + expf(x1.y - mx) + expf(x1.z - mx) + expf(x1.w - mx);
        #pragma unroll
        for (int off = 32; off > 0; off >>= 1)
            se += __shfl_xor(se, off, 64);
        const float lse = mx + logf(se);

        // ---- dot(M,x) and rowsum(M), reduced together ----
        float dot = m0.x * x0.x + m0.y * x0.y + m0.z * x0.z + m0.w * x0.w
                  + m1.x * x1.x + m1.y * x1.y + m1.z * x1.z + m1.w * x1.w;
        float rs  = m0.x + m0.y + m0.z + m0.w + m1.x + m1.y + m1.z + m1.w;
        #pragma unroll
        for (int off = 32; off > 0; off >>= 1) {
            dot += __shfl_xor(dot, off, 64);
            rs  += __shfl_xor(rs,  off, 64);
        }

        // ---- M[t], x[t]: broadcast from the owning lane (wave-uniform t) ----
        const int  k       = t & 3;
        const int  srcLane = (t >> 2) & 63;
        const bool hiHalf  = (t >= 256);
        const float cm = hiHalf ? pick4(m1, k) : pick4(m0, k);
        const float cx = hiHalf ? pick4(x1, k) : pick4(x0, k);
        const float Mt = __shfl(cm, srcLane, 64);
        const float xt = __shfl(cx, srcLane, 64);

        // ---- per-position scalar epilogue (uniform across lanes) ----
        const float L = length[b];
        const float s = 1.0f - expf(LN_0_9 / L);   // 1 - 0.9^(1/L)
        const float src = 1.0f - s * rs;
        const float contrib = s * (dot - lse * rs) + (src - s * Mt) * (xt - lse);
        acc_sum += contrib;
    }

    // every wave writes its slot unconditionally (no init required)
    if (lane == 0) {
        ws[wgid]          = acc_sum;
        ws[nwaves + wgid] = (float)acc_cnt;
    }
}

__global__ __launch_bounds__(256) void pwl_final_kernel(
    const float* __restrict__ ws, float* __restrict__ out, int nwaves)
{
    const int lane = threadIdx.x & 63;
    const int wave = threadIdx.x >> 6;

    float s = 0.0f, c = 0.0f;
    for (int i = threadIdx.x; i < nwaves; i += 256) {
        s += ws[i];
        c += ws[nwaves + i];
    }
    #pragma unroll
    for (int off = 32; off > 0; off >>= 1) {
        s += __shfl_xor(s, off, 64);
        c += __shfl_xor(c, off, 64);
    }

    __shared__ float ss[4], sc[4];
    if (lane == 0) { ss[wave] = s; sc[wave] = c; }
    __syncthreads();
    if (threadIdx.x == 0) {
        float S = ss[0] + ss[1] + ss[2] + ss[3];
        float C = sc[0] + sc[1] + sc[2] + sc[3];
        out[0] = -S / C;   // loss = sum(-contrib) / count(PAD)
    }
}

extern "C" void kernel_launch(void* const* d_in, const int* in_sizes, int n_in,
                              void* d_out, int out_size, void* d_ws, size_t ws_size,
                              hipStream_t stream) {
    const float* input  = (const float*)d_in[0];
    const int*   target = (const int*)  d_in[1];
    const float* length = (const float*)d_in[2];
    const float* matric = (const float*)d_in[3];
    float* out = (float*)d_out;
    float* ws  = (float*)d_ws;

    const int N = in_sizes[1];                 // B*T = 32768

    // 4 waves/block, 4 positions/wave -> 16 positions/block
    const int blocks = (N + 15) / 16;          // 2048 for N=32768
    const int nwaves = blocks * 4;             // 8192 partial slots

    pwl_main_kernel<<<blocks, 256, 0, stream>>>(input, target, length, matric, ws, N, nwaves);
    pwl_final_kernel<<<1, 256, 0, stream>>>(ws, out, nwaves);
}

// Round 2
// 624.292 us; speedup vs baseline: 1.2491x; 1.0095x over previous
//
#include <hip/hip_runtime.h>

// PairWiseWeightSmoothLoss — B=64, T=512, V=512, BETA=0.1, PAD=0, normalize by
// count of (target==PAD) positions.
//
// Per position n: contrib_n = s*(dot(M,x) - lse*rowsum) + (src - s*M[t])*(x[t]-lse)
//   with M = matric[forth[n], tgt[n], :], s = 1 - 0.9^(1/L[b]), src = 1 - s*rowsum.
// loss = sum over non-PAD of (-contrib) / count(PAD).
//
// v3: latency-pipelined. 4096 blocks x 4 waves; each wave owns 2 positions
// (n = wgid, wgid + nwp). ALL four row loads (x and gathered matric rows for
// both positions) are issued unconditionally BEFORE any reduction — pad/inactive
// positions read valid memory and are masked only at the accumulate. The two
// positions' butterfly chains are manually interleaved for 2-way ILP.
// Waves combine to one (sum,count) partial per block in LDS -> ws has 4096
// pairs; a single 256-thread block reduces them. No atomics, no memset.

#define T_DIM 512
#define V_DIM 512
#define LN_0_9 (-0.1053605157f) // ln(0.9)

__device__ __forceinline__ float pick4(float4 v, int k) {
    // v[k] with wave-uniform k, no dynamic register indexing (2 cndmask)
    const float lo = (k & 1) ? v.y : v.x;
    const float hi = (k & 1) ? v.w : v.z;
    return (k & 2) ? hi : lo;
}

__global__ __launch_bounds__(256) void pwl_main_kernel(
    const float* __restrict__ input,   // [N, V]
    const int*   __restrict__ target,  // [N]
    const float* __restrict__ length,  // [B]
    const float* __restrict__ matric,  // [V, V, V]
    float*       __restrict__ ws,      // [2*gridDim.x]: ws[bid]=sum, ws[nb+bid]=count
    int N, int nwp)                    // nwp = gridDim.x * 4 (position stride)
{
    const int lane = threadIdx.x & 63;
    const int wave = threadIdx.x >> 6;
    const int wgid = blockIdx.x * 4 + wave;

    // ---- wave-uniform scalar metadata for both positions ----
    int n[2] = { wgid, wgid + nwp };
    int t[2], f[2];
    #pragma unroll
    for (int p = 0; p < 2; ++p) {
        if (n[p] < N) {
            t[p] = target[n[p]];
            f[p] = ((n[p] & (T_DIM - 1)) == 0) ? 0 : target[n[p] - 1];
        } else {
            t[p] = -1;      // inactive: no sum, no count
            f[p] = 0;
            n[p] = 0;       // clamp so loads stay in-bounds
        }
    }

    // ---- hoisted row loads: all 4 rows in flight before any reduction ----
    float4 x0[2], x1[2], m0[2], m1[2];
    #pragma unroll
    for (int p = 0; p < 2; ++p) {
        const float4* xrow = (const float4*)(input + (size_t)n[p] * V_DIM);
        x0[p] = xrow[lane];
        x1[p] = xrow[lane + 64];
        const int tc = (t[p] > 0) ? t[p] : 0;
        const float4* mrow = (const float4*)(matric + ((size_t)f[p] * V_DIM + tc) * V_DIM);
        m0[p] = mrow[lane];
        m1[p] = mrow[lane + 64];
    }

    // ---- interleaved wave max ----
    float mx[2];
    #pragma unroll
    for (int p = 0; p < 2; ++p)
        mx[p] = fmaxf(fmaxf(fmaxf(x0[p].x, x0[p].y), fmaxf(x0[p].z, x0[p].w)),
                      fmaxf(fmaxf(x1[p].x, x1[p].y), fmaxf(x1[p].z, x1[p].w)));
    #pragma unroll
    for (int off = 32; off > 0; off >>= 1) {
        mx[0] = fmaxf(mx[0], __shfl_xor(mx[0], off, 64));
        mx[1] = fmaxf(mx[1], __shfl_xor(mx[1], off, 64));
    }

    // ---- interleaved sum exp(x - mx) ----
    float se[2];
    #pragma unroll
    for (int p = 0; p < 2; ++p)
        se[p] = expf(x0[p].x - mx[p]) + expf(x0[p].y - mx[p])
              + expf(x0[p].z - mx[p]) + expf(x0[p].w - mx[p])
              + expf(x1[p].x - mx[p]) + expf(x1[p].y - mx[p])
              + expf(x1[p].z - mx[p]) + expf(x1[p].w - mx[p]);
    #pragma unroll
    for (int off = 32; off > 0; off >>= 1) {
        se[0] += __shfl_xor(se[0], off, 64);
        se[1] += __shfl_xor(se[1], off, 64);
    }

    // ---- interleaved dot(M,x) and rowsum(M) ----
    float dot[2], rs[2];
    #pragma unroll
    for (int p = 0; p < 2; ++p) {
        dot[p] = m0[p].x * x0[p].x + m0[p].y * x0[p].y + m0[p].z * x0[p].z + m0[p].w * x0[p].w
               + m1[p].x * x1[p].x + m1[p].y * x1[p].y + m1[p].z * x1[p].z + m1[p].w * x1[p].w;
        rs[p]  = m0[p].x + m0[p].y + m0[p].z + m0[p].w
               + m1[p].x + m1[p].y + m1[p].z + m1[p].w;
    }
    #pragma unroll
    for (int off = 32; off > 0; off >>= 1) {
        dot[0] += __shfl_xor(dot[0], off, 64);
        dot[1] += __shfl_xor(dot[1], off, 64);
        rs[0]  += __shfl_xor(rs[0],  off, 64);
        rs[1]  += __shfl_xor(rs[1],  off, 64);
    }

    // ---- epilogue per position (wave-uniform) ----
    float acc_sum = 0.0f;
    int   acc_cnt = 0;
    #pragma unroll
    for (int p = 0; p < 2; ++p) {
        if (t[p] < 0) continue;                 // inactive tail
        if (t[p] == 0) { acc_cnt++; continue; } // PAD position
        const float lse = mx[p] + logf(se[p]);

        // M[t], x[t]: broadcast from the owning lane (wave-uniform t)
        const int  k       = t[p] & 3;
        const int  srcLane = (t[p] >> 2) & 63;
        const bool hiHalf  = (t[p] >= 256);
        const float cm = hiHalf ? pick4(m1[p], k) : pick4(m0[p], k);
        const float cx = hiHalf ? pick4(x1[p], k) : pick4(x0[p], k);
        const float Mt = __shfl(cm, srcLane, 64);
        const float xt = __shfl(cx, srcLane, 64);

        const float L = length[n[p] >> 9];          // n / T_DIM
        const float s = 1.0f - expf(LN_0_9 / L);    // 1 - 0.9^(1/L)
        const float src = 1.0f - s * rs[p];
        acc_sum += s * (dot[p] - lse * rs[p]) + (src - s * Mt) * (xt - lse);
    }

    // ---- block combine: 4 waves -> 1 partial pair ----
    __shared__ float ss[4], sc[4];
    if (lane == 0) { ss[wave] = acc_sum; sc[wave] = (float)acc_cnt; }
    __syncthreads();
    if (threadIdx.x == 0) {
        ws[blockIdx.x]             = ss[0] + ss[1] + ss[2] + ss[3];
        ws[gridDim.x + blockIdx.x] = sc[0] + sc[1] + sc[2] + sc[3];
    }
}

__global__ __launch_bounds__(256) void pwl_final_kernel(
    const float* __restrict__ ws, float* __restrict__ out, int nb)
{
    const int lane = threadIdx.x & 63;
    const int wave = threadIdx.x >> 6;

    float s = 0.0f, c = 0.0f;
    for (int i = threadIdx.x; i < nb; i += 256) {
        s += ws[i];
        c += ws[nb + i];
    }
    #pragma unroll
    for (int off = 32; off > 0; off >>= 1) {
        s += __shfl_xor(s, off, 64);
        c += __shfl_xor(c, off, 64);
    }

    __shared__ float ss[4], sc[4];
    if (lane == 0) { ss[wave] = s; sc[wave] = c; }
    __syncthreads();
    if (threadIdx.x == 0) {
        const float S = ss[0] + ss[1] + ss[2] + ss[3];
        const float C = sc[0] + sc[1] + sc[2] + sc[3];
        out[0] = -S / C;   // loss = sum(-contrib) / count(PAD)
    }
}

extern "C" void kernel_launch(void* const* d_in, const int* in_sizes, int n_in,
                              void* d_out, int out_size, void* d_ws, size_t ws_size,
                              hipStream_t stream) {
    const float* input  = (const float*)d_in[0];
    const int*   target = (const int*)  d_in[1];
    const float* length = (const float*)d_in[2];
    const float* matric = (const float*)d_in[3];
    float* out = (float*)d_out;
    float* ws  = (float*)d_ws;

    const int N = in_sizes[1];                 // B*T = 32768

    // 4 waves/block, 2 positions/wave -> 8 positions/block
    const int blocks = (N + 7) / 8;            // 4096 for N=32768
    const int nwp    = blocks * 4;             // position stride (16384)

    pwl_main_kernel<<<blocks, 256, 0, stream>>>(input, target, length, matric, ws, N, nwp);
    pwl_final_kernel<<<1, 256, 0, stream>>>(ws, out, blocks);
}